// Round 6
// baseline (119.804 us; speedup 1.0000x reference)
//
#include <hip/hip_runtime.h>
#include <hip/hip_bf16.h>

typedef short bf16x8 __attribute__((ext_vector_type(8)));
typedef short bf16x4 __attribute__((ext_vector_type(4)));
typedef float f32x4  __attribute__((ext_vector_type(4)));

#define T_AUDIO 262144
#define PADL 384
#define CUTOFF 513
#define CPAD 576       // padded mel K (513 -> 576)
#define NMELS 80

__device__ __forceinline__ unsigned short f2bf(float f){
  union { float f; unsigned u; } v; v.f = f;
  return (unsigned short)((v.u + 0x7FFFu + ((v.u >> 16) & 1u)) >> 16);
}

__device__ __forceinline__ void gload_lds16(const void* g, void* l){
  __builtin_amdgcn_global_load_lds(
      (const __attribute__((address_space(1))) unsigned int*)g,
      (__attribute__((address_space(3))) unsigned int*)l, 16, 0, 0);
}

#define BAR  __builtin_amdgcn_s_barrier()
#define WLG0 do{ asm volatile("s_waitcnt lgkmcnt(0)":::"memory"); \
                 __builtin_amdgcn_sched_barrier(0); }while(0)
#define WVM2 asm volatile("s_waitcnt vmcnt(2)":::"memory")
#define WVM0 asm volatile("s_waitcnt vmcnt(0)":::"memory")

// ---------- k_frames: framesEO [32][1024][ evens(512) | odds(512) ] bf16 ----------
// + X[256] (self-paired bin) via 2 dot-reductions + zero-pad cols 513..575
__global__ void k_frames(const float* __restrict__ audio,
                         const float* __restrict__ basis,
                         unsigned short* __restrict__ frames,
                         unsigned short* __restrict__ magT){
  __shared__ float swr[4], swi[4];
  int tid = threadIdx.x;
  int gid = blockIdx.x * 256 + tid;
  int b   = gid >> 17;
  int rem = gid & 131071;
  int t   = rem >> 7;
  int k0  = (rem & 127) << 3;
  int s0  = t * 256 + k0 - PADL;
  const float* ap = audio + (long)b * T_AUDIO;
  float v[8];
  if (s0 >= 0 && s0 + 7 < T_AUDIO){
    f32x4 a0 = *(const f32x4*)(ap + s0);
    f32x4 a1 = *(const f32x4*)(ap + s0 + 4);
    v[0]=a0[0]; v[1]=a0[1]; v[2]=a0[2]; v[3]=a0[3];
    v[4]=a1[0]; v[5]=a1[1]; v[6]=a1[2]; v[7]=a1[3];
  } else {
    #pragma unroll
    for (int e = 0; e < 8; ++e){
      int s = s0 + e;
      if (s < 0) s = -s;
      if (s >= T_AUDIO) s = 2*(T_AUDIO-1) - s;
      v[e] = ap[s];
    }
  }
  bf16x4 ev, od;
  #pragma unroll
  for (int e = 0; e < 4; ++e){
    ev[e] = (short)f2bf(v[2*e]);
    od[e] = (short)f2bf(v[2*e+1]);
  }
  long fb = ((long)b << 20) + t * 1024;
  *(bf16x4*)(frames + fb + (k0 >> 1))       = ev;
  *(bf16x4*)(frames + fb + 512 + (k0 >> 1)) = od;

  // X[256]: real row = basis[256], imag row = basis[769]
  const float* r256 = basis + 256 * 1024 + k0;
  const float* i256 = basis + 769 * 1024 + k0;
  float dr = 0.f, di = 0.f;
  #pragma unroll
  for (int e = 0; e < 8; ++e){ dr += v[e]*r256[e]; di += v[e]*i256[e]; }
  #pragma unroll
  for (int off = 32; off; off >>= 1){
    dr += __shfl_down(dr, off, 64);
    di += __shfl_down(di, off, 64);
  }
  int lane = tid & 63, wid = tid >> 6;
  if (lane == 0){ swr[wid] = dr; swi[wid] = di; }
  __syncthreads();
  long tg = (long)b * 1024 + t;
  if (tid == 0 || tid == 128){
    float R = (tid == 0) ? (swr[0] + swr[1]) : (swr[2] + swr[3]);
    float I = (tid == 0) ? (swi[0] + swi[1]) : (swi[2] + swi[3]);
    magT[tg * CPAD + 256] = f2bf(sqrtf(R*R + I*I));
  }
  int c = tid & 127;
  if (c < 63) magT[tg * CPAD + 513 + c] = 0;
}

// ---------- k_basis4: frag-major A  bi3[e][g][wm][s][i][lane] 16B chunks ----------
// chunk CI -> lane l=CI&63, i=(CI>>6)&3, s=(CI>>8)&15, wm=(CI>>12)&1, g=(CI>>13)&3, e=CI>>15
// value: interleaved row RI=g*128+wm*64+i*16+(l&15); c=RI>>1, part=RI&1;
//        k=s*32+(l>>4)*8+jj, sample n=2k+e  -> basis[c+513*part][n]
__global__ void k_basis4(const float* __restrict__ basis, unsigned short* __restrict__ bi3){
  int CI = blockIdx.x * 256 + threadIdx.x;     // 65536 chunks
  int l  = CI & 63;
  int i  = (CI >> 6) & 3;
  int s  = (CI >> 8) & 15;
  int wm = (CI >> 12) & 1;
  int g  = (CI >> 13) & 3;
  int e  = CI >> 15;
  int RI = g * 128 + wm * 64 + i * 16 + (l & 15);
  int srcr = (RI >> 1) + 513 * (RI & 1);
  const float* sp = basis + srcr * 1024 + 2 * (s * 32 + (l >> 4) * 8) + e;
  bf16x8 o;
  #pragma unroll
  for (int jj = 0; jj < 8; ++jj) o[jj] = (short)f2bf(sp[2*jj]);
  *(bf16x8*)(bi3 + (long)CI * 8) = o;
}

// ---------- k_w: mel weights [80][576] bf16, zero-padded ----------
__global__ void k_w(const float* __restrict__ w, unsigned short* __restrict__ wb){
  int gid = blockIdx.x * 256 + threadIdx.x;
  if (gid >= NMELS * CPAD) return;
  int m = gid / CPAD, c = gid % CPAD;
  float v = (c < CUTOFF) ? w[m * CUTOFF + c] : 0.f;
  wb[gid] = f2bf(v);
}

// ---------- k_stft: E/O GEMM, A direct-from-L2 to regs, B LDS ring-2 ----------
// M=1024 (256/block: g-group), N=32768 (256/block), K=512, BK=32
// LDS buffer d (32KB): B-even [0,16K) 256r x 64B | B-odd [16K,32K); swz ch^((row>>1)&3)
__launch_bounds__(512, 2)
__global__ void k_stft(const unsigned short* __restrict__ bi3,
                       const unsigned short* __restrict__ frames,
                       unsigned short* __restrict__ magT){
  __shared__ __align__(16) char LDS[65536];
  const int tid = threadIdx.x;
  const int l   = tid & 63, w = tid >> 6;
  const int wm  = w >> 2, wn = w & 3;

  int bx = blockIdx.x;
  int sw = ((bx & 7) << 6) | (bx >> 3);       // XCD swizzle (512 % 8 == 0, bijective)
  const int g  = sw & 3;                      // c-group
  const int n0 = (sw >> 2) << 8;

  // ---- B stage side: dest linear (tid*16), source pre-swizzled ----
  const int srow = tid >> 2;                                  // 0..127
  const int cs16 = (((tid & 3) ^ ((tid >> 3) & 3)) << 4);
  const char* Bg0 = (const char*)frames + (long)(n0 + srow) * 2048 + cs16;
  // even k-tile s: bytes [s*64,+64) of row's first 1KB; odd half at +1024; rows 128.. at +262144
  #define STBE(d_, kb_) do{ char* L_ = LDS + (d_)*32768 + tid*16; \
      gload_lds16(Bg0 + (kb_),          L_); \
      gload_lds16(Bg0 + 262144 + (kb_), L_ + 8192); }while(0)
  #define STBO(d_, kb_) do{ char* L_ = LDS + (d_)*32768 + tid*16; \
      gload_lds16(Bg0 + 1024 + (kb_),          L_ + 16384); \
      gload_lds16(Bg0 + 262144 + 1024 + (kb_), L_ + 24576); }while(0)

  // ---- B read side ----
  const int x  = l & 15;
  const int ch = (((l >> 4) ^ ((x >> 1) & 3)) << 4);
  const char* Bb0 = LDS + (wn * 64 + x) * 64 + ch;            // + d*32768 (+16384 for odd)

  // ---- A read side: frag-major global, one coalesced dwordx4 per frag ----
  const char* AgE = (const char*)bi3 + ((long)((0*4 + g)*2 + wm) * 16) * 4096 + l*16;
  const char* AgO = (const char*)bi3 + ((long)((1*4 + g)*2 + wm) * 16) * 4096 + l*16;

  f32x4 accE[4][4] = {}, accO[4][4] = {};
  bf16x8 af[4], bq[4];

  #define MME(ACC) do{ __builtin_amdgcn_s_setprio(1); _Pragma("unroll") \
    for (int i_ = 0; i_ < 4; ++i_){ _Pragma("unroll") \
      for (int j_ = 0; j_ < 4; ++j_) \
        ACC[i_][j_] = __builtin_amdgcn_mfma_f32_16x16x32_bf16(af[i_], bq[j_], ACC[i_][j_], 0, 0, 0); } \
    __builtin_amdgcn_s_setprio(0); }while(0)

  // ---- prologue: stage step 0 (both halves) into buf 0 ----
  STBE(0, 0); STBO(0, 0);
  WVM0;
  BAR;

  #pragma unroll
  for (int s = 0; s < 16; ++s){
    const int d   = s & 1, dn = d ^ 1;
    const int kbn = ((s + 1) & 15) * 64;     // wraps on last iter: redundant but safe
    const char* Bb = Bb0 + d * 32768;

    // ---- phase E: A-E frags (global), B-even frags (LDS), stage next B-even ----
    #pragma unroll
    for (int i_ = 0; i_ < 4; ++i_) af[i_] = *(const bf16x8*)(AgE + s*4096 + i_*1024);
    #pragma unroll
    for (int j_ = 0; j_ < 4; ++j_) bq[j_] = *(const bf16x8*)(Bb + j_*1024);
    STBE(dn, kbn);
    BAR;
    WVM2; WLG0;
    MME(accE);
    BAR;

    // ---- phase O: A-O frags, B-odd frags, stage next B-odd ----
    #pragma unroll
    for (int i_ = 0; i_ < 4; ++i_) af[i_] = *(const bf16x8*)(AgO + s*4096 + i_*1024);
    #pragma unroll
    for (int j_ = 0; j_ < 4; ++j_) bq[j_] = *(const bf16x8*)(Bb + 16384 + j_*1024);
    STBO(dn, kbn);
    BAR;
    WVM2; WLG0;
    MME(accO);
    BAR;
  }

  // ---- epilogue: X[c]=E+O, X[512-c]=conj(E)-conj(O) -> |.| ----
  const long tbase = (long)(n0 + wn * 64 + x);
  const int  q4 = (l >> 4) << 2;
  #pragma unroll
  for (int i = 0; i < 4; ++i){
    int mrow = wm * 64 + i * 16 + q4;       // multiple of 4
    int c0 = g * 64 + (mrow >> 1);          // even, 0..254
    #pragma unroll
    for (int j = 0; j < 4; ++j){
      long t = tbase + j * 16;
      f32x4 E = accE[i][j], O = accO[i][j];
      float m1 = sqrtf((E[0]+O[0])*(E[0]+O[0]) + (E[1]+O[1])*(E[1]+O[1]));  // X[c0]
      float m2 = sqrtf((E[2]+O[2])*(E[2]+O[2]) + (E[3]+O[3])*(E[3]+O[3]));  // X[c0+1]
      float m3 = sqrtf((E[0]-O[0])*(E[0]-O[0]) + (E[1]-O[1])*(E[1]-O[1]));  // X[512-c0]
      float m4 = sqrtf((E[2]-O[2])*(E[2]-O[2]) + (E[3]-O[3])*(E[3]-O[3]));  // X[511-c0]
      unsigned pack = (unsigned)f2bf(m1) | ((unsigned)f2bf(m2) << 16);
      *(unsigned*)(magT + t * CPAD + c0) = pack;
      magT[t * CPAD + 512 - c0] = f2bf(m3);
      magT[t * CPAD + 511 - c0] = f2bf(m4);
    }
  }
  #undef STBE
  #undef STBO
  #undef MME
}

// ---------- k_mel: [80][576] x [576][t] + log(clip) -> out [32][80][1024] f32 ----------
__launch_bounds__(256)
__global__ void k_mel(const unsigned short* __restrict__ wb,
                      const unsigned short* __restrict__ magT,
                      float* __restrict__ out){
  __shared__ unsigned short Ws[80 * 32];
  __shared__ unsigned short Ms[128 * 32];
  int tid  = threadIdx.x, lane = tid & 63, wid = tid >> 6;
  int bx   = blockIdx.x;
  int bt   = bx & 7, b = bx >> 3;
  int t0   = bt * 128;
  f32x4 acc[5][2] = {};
  const char* Mb = (const char*)(magT + ((long)b * 1024 + t0) * CPAD);
  const char* Wb = (const char*)wb;

  for (int kt = 0; kt < 18; ++kt){
    int k0b = kt * 64;
    {
      int o = tid * 16;
      gload_lds16(Wb + (o >> 6) * 1152 + k0b + (o & 63), (char*)Ws + wid * 1024);
      if (wid == 0){
        int o2 = 4096 + lane * 16;
        gload_lds16(Wb + (o2 >> 6) * 1152 + k0b + (o2 & 63), (char*)Ws + 4096);
      }
    }
    #pragma unroll
    for (int q = 0; q < 2; ++q){
      int o = (q * 256 + tid) * 16;
      gload_lds16(Mb + (long)(o >> 6) * 1152 + k0b + (o & 63), (char*)Ms + q * 4096 + wid * 1024);
    }
    __syncthreads();
    bf16x8 af[5], bfr[2];
    int kb = (lane >> 4) << 4;
    #pragma unroll
    for (int i = 0; i < 5; ++i)
      af[i] = *(const bf16x8*)((const char*)Ws + (i*16 + (lane & 15)) * 64 + kb);
    #pragma unroll
    for (int j = 0; j < 2; ++j)
      bfr[j] = *(const bf16x8*)((const char*)Ms + (wid*32 + j*16 + (lane & 15)) * 64 + kb);
    #pragma unroll
    for (int i = 0; i < 5; ++i)
      #pragma unroll
      for (int j = 0; j < 2; ++j)
        acc[i][j] = __builtin_amdgcn_mfma_f32_16x16x32_bf16(af[i], bfr[j], acc[i][j], 0, 0, 0);
    __syncthreads();
  }
  #pragma unroll
  for (int i = 0; i < 5; ++i)
    #pragma unroll
    for (int j = 0; j < 2; ++j){
      int m = i*16 + ((lane >> 4) << 2);
      int t = t0 + wid*32 + j*16 + (lane & 15);
      #pragma unroll
      for (int r = 0; r < 4; ++r){
        float v = acc[i][j][r];
        out[((long)b * NMELS + (m + r)) * 1024 + t] = logf(fmaxf(v, 1e-5f));
      }
    }
}

__global__ void k_sentinel(float* out, int n){
  int i = blockIdx.x * 256 + threadIdx.x;
  if (i < n) out[i] = 12345.0f;
}

extern "C" void kernel_launch(void* const* d_in, const int* in_sizes, int n_in,
                              void* d_out, int out_size, void* d_ws, size_t ws_size,
                              hipStream_t stream){
  const float* audio = (const float*)d_in[0];
  const float* basis = (const float*)d_in[1];
  const float* melw  = (const float*)d_in[2];
  float* out = (float*)d_out;

  size_t off_frames = 0;
  size_t off_bi     = off_frames + (size_t)32 * 1024 * 1024 * 2;   // 67,108,864
  size_t off_wb     = off_bi     + (size_t)1024 * 1024 * 2;        // slot 2 MB (bi3 uses 1 MB)
  size_t off_mag    = off_wb     + (size_t)NMELS * CPAD * 2;
  size_t total      = off_mag    + (size_t)32 * 1024 * CPAD * 2;   // = 107,046,912

  if (ws_size < total){
    k_sentinel<<<(out_size + 255) / 256, 256, 0, stream>>>(out, out_size);
    return;
  }
  char* ws = (char*)d_ws;
  unsigned short* frames = (unsigned short*)(ws + off_frames);
  unsigned short* bi3    = (unsigned short*)(ws + off_bi);
  unsigned short* wb     = (unsigned short*)(ws + off_wb);
  unsigned short* magT   = (unsigned short*)(ws + off_mag);

  k_frames<<<16384, 256, 0, stream>>>(audio, basis, frames, magT);
  k_basis4<<<  256, 256, 0, stream>>>(basis, bi3);
  k_w     <<<  180, 256, 0, stream>>>(melw, wb);
  k_stft  <<<  512, 512, 0, stream>>>(bi3, frames, magT);
  k_mel   <<<  256, 256, 0, stream>>>(wb, magT, out);
}

// Round 8
// 101.479 us; speedup vs baseline: 1.1806x; 1.1806x over previous
//
#include <hip/hip_runtime.h>
#include <hip/hip_bf16.h>

typedef short bf16x8 __attribute__((ext_vector_type(8)));
typedef short bf16x4 __attribute__((ext_vector_type(4)));
typedef float f32x4  __attribute__((ext_vector_type(4)));

#define T_AUDIO 262144
#define PADL 384
#define CUTOFF 513
#define CPAD 576       // padded mel K (513 -> 576)
#define NMELS 80

__device__ __forceinline__ unsigned short f2bf(float f){
  union { float f; unsigned u; } v; v.f = f;
  return (unsigned short)((v.u + 0x7FFFu + ((v.u >> 16) & 1u)) >> 16);
}

__device__ __forceinline__ void gload_lds16(const void* g, void* l){
  __builtin_amdgcn_global_load_lds(
      (const __attribute__((address_space(1))) unsigned int*)g,
      (__attribute__((address_space(3))) unsigned int*)l, 16, 0, 0);
}

#define BAR  __builtin_amdgcn_s_barrier()
#define WLG0 do{ asm volatile("s_waitcnt lgkmcnt(0)":::"memory"); \
                 __builtin_amdgcn_sched_barrier(0); }while(0)
#define WVM4 asm volatile("s_waitcnt vmcnt(4)":::"memory")

// ---------- k_frames: framesEO [32][1024][ evens(512) | odds(512) ] bf16 ----------
// + X[256] (self-paired bin) via 2 dot-reductions + zero-pad cols 513..575
__global__ void k_frames(const float* __restrict__ audio,
                         const float* __restrict__ basis,
                         unsigned short* __restrict__ frames,
                         unsigned short* __restrict__ magT){
  __shared__ float swr[4], swi[4];
  int tid = threadIdx.x;
  int gid = blockIdx.x * 256 + tid;
  int b   = gid >> 17;
  int rem = gid & 131071;
  int t   = rem >> 7;
  int k0  = (rem & 127) << 3;
  int s0  = t * 256 + k0 - PADL;
  const float* ap = audio + (long)b * T_AUDIO;
  float v[8];
  if (s0 >= 0 && s0 + 7 < T_AUDIO){
    f32x4 a0 = *(const f32x4*)(ap + s0);
    f32x4 a1 = *(const f32x4*)(ap + s0 + 4);
    v[0]=a0[0]; v[1]=a0[1]; v[2]=a0[2]; v[3]=a0[3];
    v[4]=a1[0]; v[5]=a1[1]; v[6]=a1[2]; v[7]=a1[3];
  } else {
    #pragma unroll
    for (int e = 0; e < 8; ++e){
      int s = s0 + e;
      if (s < 0) s = -s;
      if (s >= T_AUDIO) s = 2*(T_AUDIO-1) - s;
      v[e] = ap[s];
    }
  }
  bf16x4 ev, od;
  #pragma unroll
  for (int e = 0; e < 4; ++e){
    ev[e] = (short)f2bf(v[2*e]);
    od[e] = (short)f2bf(v[2*e+1]);
  }
  long fb = ((long)b << 20) + t * 1024;
  *(bf16x4*)(frames + fb + (k0 >> 1))       = ev;
  *(bf16x4*)(frames + fb + 512 + (k0 >> 1)) = od;

  // X[256]: real row = basis[256], imag row = basis[769]
  const float* r256 = basis + 256 * 1024 + k0;
  const float* i256 = basis + 769 * 1024 + k0;
  float dr = 0.f, di = 0.f;
  #pragma unroll
  for (int e = 0; e < 8; ++e){ dr += v[e]*r256[e]; di += v[e]*i256[e]; }
  #pragma unroll
  for (int off = 32; off; off >>= 1){
    dr += __shfl_down(dr, off, 64);
    di += __shfl_down(di, off, 64);
  }
  int lane = tid & 63, wid = tid >> 6;
  if (lane == 0){ swr[wid] = dr; swi[wid] = di; }
  __syncthreads();
  long tg = (long)b * 1024 + t;
  if (tid == 0 || tid == 128){
    float R = (tid == 0) ? (swr[0] + swr[1]) : (swr[2] + swr[3]);
    float I = (tid == 0) ? (swi[0] + swi[1]) : (swi[2] + swi[3]);
    magT[tg * CPAD + 256] = f2bf(sqrtf(R*R + I*I));
  }
  int c = tid & 127;
  if (c < 63) magT[tg * CPAD + 513 + c] = 0;
}

// ---------- k_basis3: bi2 [1024][512] bf16 ----------
// rows 0..511  = E: row R -> c=R>>1, part=R&1, samples n=2m   (src basis[c+513*part])
// rows 512..   = O: same with n=2m+1
__global__ void k_basis3(const float* __restrict__ basis, unsigned short* __restrict__ bi2){
  int gid = blockIdx.x * 256 + threadIdx.x;   // 1024 * 64
  int R  = gid >> 6;
  int m0 = (gid & 63) << 3;
  int half = R >> 9, Rl = R & 511;
  int srcr = (Rl >> 1) + 513 * (Rl & 1);
  const float* sp = basis + srcr * 1024 + 2 * m0 + half;
  bf16x8 o;
  #pragma unroll
  for (int e = 0; e < 8; ++e) o[e] = (short)f2bf(sp[2*e]);
  *(bf16x8*)(bi2 + R * 512 + m0) = o;
}

// ---------- k_w: mel weights [80][576] bf16, zero-padded ----------
__global__ void k_w(const float* __restrict__ w, unsigned short* __restrict__ wb){
  int gid = blockIdx.x * 256 + threadIdx.x;
  if (gid >= NMELS * CPAD) return;
  int m = gid / CPAD, c = gid % CPAD;
  float v = (c < CUTOFF) ? w[m * CUTOFF + c] : 0.f;
  wb[gid] = f2bf(v);
}

// ---------- k_stft: E/O GEMM, 128x128 tile, 4 waves, ring-3 LDS, 2 blocks/CU ----------
// M=512 interleaved rows (4 g-groups of 128 -> c in [g*64, g*64+64)), N=32768, K=512
// 32 virtual steps: v -> parity p=v&1 (E/O), k-slice kk=v>>1
// LDS buffer (16KB): A-X [0,8K) 128r x 64B | B-X [8K,16K) 128r x 64B; ring of 3 = 48KB
// swizzle: lds[row][ch] = glob[row][ch ^ ((row>>1)&3)] (both sides)
__launch_bounds__(256, 2)
__global__ void k_stft(const unsigned short* __restrict__ bi2,
                       const unsigned short* __restrict__ frames,
                       unsigned short* __restrict__ magT){
  __shared__ __align__(16) char LDS[49152];
  const int tid = threadIdx.x;
  const int l   = tid & 63, w = tid >> 6;
  const int wm  = w >> 1, wn = w & 1;

  int bx = blockIdx.x;
  int sw = ((bx & 7) << 7) | (bx >> 3);     // XCD swizzle (1024 % 8 == 0, bijective)
  const int g  = sw & 3;                    // M-tile: interleaved rows [g*128, +128)  (c in [g*64,+64))
  const int n0 = (sw >> 2) << 7;            // frame tile [n0, n0+128)

  // ---- stage side: dest linear (tid*16), source pre-swizzled ----
  const int srow = tid >> 2;                                  // 0..63
  const int cs16 = (((tid & 3) ^ ((tid >> 3) & 3)) << 4);
  const char* Ag = (const char*)bi2    + (long)(g * 128 + srow) * 1024 + cs16;   // E rows; O at +524288
  const char* Bg = (const char*)frames + (long)(n0 + srow) * 2048 + cs16;
  char* Ld = LDS + tid * 16;
  // step v: A byte off = (v&1)*524288 + (v>>1)*64 ; B byte off = (v&1)*1024 + (v>>1)*64
  #define STG(d_, ab_, bb_) do{ \
    gload_lds16(Ag + (ab_),          Ld + (d_)*16384); \
    gload_lds16(Ag + 65536 + (ab_),  Ld + (d_)*16384 + 4096); \
    gload_lds16(Bg + (bb_),          Ld + (d_)*16384 + 8192); \
    gload_lds16(Bg + 131072 + (bb_), Ld + (d_)*16384 + 12288); }while(0)

  // ---- read side ----
  const int x  = l & 15;
  const int ch = (((l >> 4) ^ ((x >> 1) & 3)) << 4);
  const char* Ar = LDS + (wm * 64 + x) * 64 + ch;             // + d*16384 + i*1024
  const char* Br = LDS + 8192 + (wn * 64 + x) * 64 + ch;      // + d*16384 + j*1024

  f32x4 accE[4][4] = {}, accO[4][4] = {};
  bf16x8 af[4], bq[4];

  #define MME(ACC) do{ __builtin_amdgcn_s_setprio(1); _Pragma("unroll") \
    for (int i_ = 0; i_ < 4; ++i_){ _Pragma("unroll") \
      for (int j_ = 0; j_ < 4; ++j_) \
        ACC[i_][j_] = __builtin_amdgcn_mfma_f32_16x16x32_bf16(af[i_], bq[j_], ACC[i_][j_], 0, 0, 0); } \
    __builtin_amdgcn_s_setprio(0); }while(0)

  // ---- prologue: stage v=0 -> buf0, v=1 -> buf1; wait v0 (4 outstanding = v1) ----
  STG(0, 0, 0);
  STG(1, 524288, 1024);
  WVM4;
  BAR;

  #pragma unroll
  for (int v = 0; v < 32; ++v){
    const int d  = v % 3;
    const int v2 = (v + 2) & 31;            // tail wraps: harmless re-stage of consumed bufs
    const int a2 = (v2 & 1) * 524288 + (v2 >> 1) * 64;
    const int b2 = (v2 & 1) * 1024   + (v2 >> 1) * 64;
    STG((v + 2) % 3, a2, b2);

    const char* Ab = Ar + d * 16384;
    const char* Bb = Br + d * 16384;
    #pragma unroll
    for (int i_ = 0; i_ < 4; ++i_) af[i_] = *(const bf16x8*)(Ab + i_ * 1024);
    #pragma unroll
    for (int j_ = 0; j_ < 4; ++j_) bq[j_] = *(const bf16x8*)(Bb + j_ * 1024);
    WLG0;
    if (v & 1){ MME(accO); } else { MME(accE); }
    WVM4;                                    // counted: only stage(v+2) stays in flight
    BAR;
  }

  // ---- epilogue: X[c]=E+O, X[512-c]=conj(E)-conj(O) -> |.| ----
  const long tbase = (long)(n0 + wn * 64 + x);
  const int  q4 = (l >> 4) << 2;
  #pragma unroll
  for (int i = 0; i < 4; ++i){
    int mrow = wm * 64 + i * 16 + q4;       // multiple of 4
    int c0 = (g * 128 + mrow) >> 1;         // even, 0..254
    #pragma unroll
    for (int j = 0; j < 4; ++j){
      long t = tbase + j * 16;
      f32x4 E = accE[i][j], O = accO[i][j];
      float m1 = sqrtf((E[0]+O[0])*(E[0]+O[0]) + (E[1]+O[1])*(E[1]+O[1]));  // X[c0]
      float m2 = sqrtf((E[2]+O[2])*(E[2]+O[2]) + (E[3]+O[3])*(E[3]+O[3]));  // X[c0+1]
      float m3 = sqrtf((E[0]-O[0])*(E[0]-O[0]) + (E[1]-O[1])*(E[1]-O[1]));  // X[512-c0]
      float m4 = sqrtf((E[2]-O[2])*(E[2]-O[2]) + (E[3]-O[3])*(E[3]-O[3]));  // X[511-c0]
      unsigned pack = (unsigned)f2bf(m1) | ((unsigned)f2bf(m2) << 16);
      *(unsigned*)(magT + t * CPAD + c0) = pack;
      magT[t * CPAD + 512 - c0] = f2bf(m3);
      magT[t * CPAD + 511 - c0] = f2bf(m4);
    }
  }
  #undef STG
  #undef MME
}

// ---------- k_mel: [80][576] x [576][t] + log(clip) -> out [32][80][1024] f32 ----------
__launch_bounds__(256)
__global__ void k_mel(const unsigned short* __restrict__ wb,
                      const unsigned short* __restrict__ magT,
                      float* __restrict__ out){
  __shared__ unsigned short Ws[80 * 32];
  __shared__ unsigned short Ms[128 * 32];
  int tid  = threadIdx.x, lane = tid & 63, wid = tid >> 6;
  int bx   = blockIdx.x;
  int bt   = bx & 7, b = bx >> 3;
  int t0   = bt * 128;
  f32x4 acc[5][2] = {};
  const char* Mb = (const char*)(magT + ((long)b * 1024 + t0) * CPAD);
  const char* Wb = (const char*)wb;

  for (int kt = 0; kt < 18; ++kt){
    int k0b = kt * 64;
    {
      int o = tid * 16;
      gload_lds16(Wb + (o >> 6) * 1152 + k0b + (o & 63), (char*)Ws + wid * 1024);
      if (wid == 0){
        int o2 = 4096 + lane * 16;
        gload_lds16(Wb + (o2 >> 6) * 1152 + k0b + (o2 & 63), (char*)Ws + 4096);
      }
    }
    #pragma unroll
    for (int q = 0; q < 2; ++q){
      int o = (q * 256 + tid) * 16;
      gload_lds16(Mb + (long)(o >> 6) * 1152 + k0b + (o & 63), (char*)Ms + q * 4096 + wid * 1024);
    }
    __syncthreads();
    bf16x8 af[5], bfr[2];
    int kb = (lane >> 4) << 4;
    #pragma unroll
    for (int i = 0; i < 5; ++i)
      af[i] = *(const bf16x8*)((const char*)Ws + (i*16 + (lane & 15)) * 64 + kb);
    #pragma unroll
    for (int j = 0; j < 2; ++j)
      bfr[j] = *(const bf16x8*)((const char*)Ms + (wid*32 + j*16 + (lane & 15)) * 64 + kb);
    #pragma unroll
    for (int i = 0; i < 5; ++i)
      #pragma unroll
      for (int j = 0; j < 2; ++j)
        acc[i][j] = __builtin_amdgcn_mfma_f32_16x16x32_bf16(af[i], bfr[j], acc[i][j], 0, 0, 0);
    __syncthreads();
  }
  #pragma unroll
  for (int i = 0; i < 5; ++i)
    #pragma unroll
    for (int j = 0; j < 2; ++j){
      int m = i*16 + ((lane >> 4) << 2);
      int t = t0 + wid*32 + j*16 + (lane & 15);
      #pragma unroll
      for (int r = 0; r < 4; ++r){
        float v = acc[i][j][r];
        out[((long)b * NMELS + (m + r)) * 1024 + t] = logf(fmaxf(v, 1e-5f));
      }
    }
}

__global__ void k_sentinel(float* out, int n){
  int i = blockIdx.x * 256 + threadIdx.x;
  if (i < n) out[i] = 12345.0f;
}

extern "C" void kernel_launch(void* const* d_in, const int* in_sizes, int n_in,
                              void* d_out, int out_size, void* d_ws, size_t ws_size,
                              hipStream_t stream){
  const float* audio = (const float*)d_in[0];
  const float* basis = (const float*)d_in[1];
  const float* melw  = (const float*)d_in[2];
  float* out = (float*)d_out;

  size_t off_frames = 0;
  size_t off_bi     = off_frames + (size_t)32 * 1024 * 1024 * 2;   // 67,108,864
  size_t off_wb     = off_bi     + (size_t)1024 * 1024 * 2;        // slot 2 MB (bi2 uses 1 MB)
  size_t off_mag    = off_wb     + (size_t)NMELS * CPAD * 2;
  size_t total      = off_mag    + (size_t)32 * 1024 * CPAD * 2;   // = 107,046,912

  if (ws_size < total){
    k_sentinel<<<(out_size + 255) / 256, 256, 0, stream>>>(out, out_size);
    return;
  }
  char* ws = (char*)d_ws;
  unsigned short* frames = (unsigned short*)(ws + off_frames);
  unsigned short* bi2    = (unsigned short*)(ws + off_bi);
  unsigned short* wb     = (unsigned short*)(ws + off_wb);
  unsigned short* magT   = (unsigned short*)(ws + off_mag);

  k_frames<<<16384, 256, 0, stream>>>(audio, basis, frames, magT);
  k_basis3<<<  256, 256, 0, stream>>>(basis, bi2);
  k_w     <<<  180, 256, 0, stream>>>(melw, wb);
  k_stft  <<< 1024, 256, 0, stream>>>(bi2, frames, magT);
  k_mel   <<<  256, 256, 0, stream>>>(wb, magT, out);
}

// Round 9
// 88.539 us; speedup vs baseline: 1.3531x; 1.1462x over previous
//
#include <hip/hip_runtime.h>
#include <hip/hip_bf16.h>

typedef short bf16x8 __attribute__((ext_vector_type(8)));
typedef float f32x4  __attribute__((ext_vector_type(4)));

#define T_AUDIO 262144
#define PADL 384
#define CUTOFF 513
#define CPAD 576       // padded mel K (513 -> 576)
#define NMELS 80
#define SEGLEN 33536   // 127*256 + 1024 samples per 128-frame tile
#define EBYTES 33536   // SEGLEN/2 bf16 = bytes per parity plane in LDS

__device__ __forceinline__ unsigned short f2bf(float f){
  union { float f; unsigned u; } v; v.f = f;
  return (unsigned short)((v.u + 0x7FFFu + ((v.u >> 16) & 1u)) >> 16);
}

__device__ __forceinline__ void gload_lds16(const void* g, void* l){
  __builtin_amdgcn_global_load_lds(
      (const __attribute__((address_space(1))) unsigned int*)g,
      (__attribute__((address_space(3))) unsigned int*)l, 16, 0, 0);
}

// ---------- k_extra: bin-256 column (f32 dot) + zero-pad cols 513..575 ----------
__global__ void k_extra(const float* __restrict__ audio,
                        const float* __restrict__ basis,
                        unsigned short* __restrict__ magT){
  __shared__ float swr[4], swi[4];
  int tid = threadIdx.x;
  int gid = blockIdx.x * 256 + tid;
  int b   = gid >> 17;
  int rem = gid & 131071;
  int t   = rem >> 7;
  int k0  = (rem & 127) << 3;
  int s0  = t * 256 + k0 - PADL;
  const float* ap = audio + (long)b * T_AUDIO;
  float v[8];
  if (s0 >= 0 && s0 + 7 < T_AUDIO){
    f32x4 a0 = *(const f32x4*)(ap + s0);
    f32x4 a1 = *(const f32x4*)(ap + s0 + 4);
    v[0]=a0[0]; v[1]=a0[1]; v[2]=a0[2]; v[3]=a0[3];
    v[4]=a1[0]; v[5]=a1[1]; v[6]=a1[2]; v[7]=a1[3];
  } else {
    #pragma unroll
    for (int e = 0; e < 8; ++e){
      int s = s0 + e;
      if (s < 0) s = -s;
      if (s >= T_AUDIO) s = 2*(T_AUDIO-1) - s;
      v[e] = ap[s];
    }
  }
  const float* r256 = basis + 256 * 1024 + k0;
  const float* i256 = basis + 769 * 1024 + k0;
  float dr = 0.f, di = 0.f;
  #pragma unroll
  for (int e = 0; e < 8; ++e){ dr += v[e]*r256[e]; di += v[e]*i256[e]; }
  #pragma unroll
  for (int off = 32; off; off >>= 1){
    dr += __shfl_down(dr, off, 64);
    di += __shfl_down(di, off, 64);
  }
  int lane = tid & 63, wid = tid >> 6;
  if (lane == 0){ swr[wid] = dr; swi[wid] = di; }
  __syncthreads();
  long tg = (long)b * 1024 + t;
  if (tid == 0 || tid == 128){
    float R = (tid == 0) ? (swr[0] + swr[1]) : (swr[2] + swr[3]);
    float I = (tid == 0) ? (swi[0] + swi[1]) : (swi[2] + swi[3]);
    magT[tg * CPAD + 256] = f2bf(sqrtf(R*R + I*I));
  }
  int c = tid & 127;
  if (c < 63) magT[tg * CPAD + 513 + c] = 0;
}

// ---------- k_basis4: frag-major A  bi2f[(((g*2+p)*16+s)*8+f)*64+l] 16B chunks ----------
// chunk -> interleaved row R = g*128 + (f>>2)*64 + (f&3)*16 + (l&15); c=R>>1, part=R&1
//          k = s*32 + (l>>4)*8 + e ; sample n = 2k+p ; value = basis[c+513*part][n]
__global__ void k_basis4(const float* __restrict__ basis, unsigned short* __restrict__ bi2f){
  int CI = blockIdx.x * 256 + threadIdx.x;     // 65536 chunks
  int l  = CI & 63;
  int f  = (CI >> 6) & 7;
  int s  = (CI >> 9) & 15;
  int p  = (CI >> 13) & 1;
  int g  = CI >> 14;
  int R  = g * 128 + (f >> 2) * 64 + (f & 3) * 16 + (l & 15);
  int srcr = (R >> 1) + 513 * (R & 1);
  const float* sp = basis + srcr * 1024 + 2 * (s * 32 + (l >> 4) * 8) + p;
  bf16x8 o;
  #pragma unroll
  for (int e = 0; e < 8; ++e) o[e] = (short)f2bf(sp[2*e]);
  *(bf16x8*)(bi2f + (long)CI * 8) = o;
}

// ---------- k_w: mel weights [80][576] bf16, zero-padded ----------
__global__ void k_w(const float* __restrict__ w, unsigned short* __restrict__ wb){
  int gid = blockIdx.x * 256 + threadIdx.x;
  if (gid >= NMELS * CPAD) return;
  int m = gid / CPAD, c = gid % CPAD;
  float v = (c < CUTOFF) ? w[m * CUTOFF + c] : 0.f;
  wb[gid] = f2bf(v);
}

// ---------- k_stft: barrier-free E/O GEMM ----------
// Block: 128 interleaved M-rows (g) x 128 frames (nt), K=512 per parity.
// LDS: audio segment, E/O split, bf16, XOR-swizzled (chunk C at C^((C>>4)&15)).
// A: direct global frag-major (L2-resident), 1-step register-ring prefetch.
// ONE barrier total (after audio staging); 16 steps x 32 MFMA free-running.
__launch_bounds__(256, 2)
__global__ void k_stft(const unsigned short* __restrict__ bi2f,
                       const float* __restrict__ audio,
                       unsigned short* __restrict__ magT){
  __shared__ __align__(16) char LDS[2 * EBYTES];   // evens | odds
  const int tid = threadIdx.x;
  const int l   = tid & 63, w = tid >> 6;
  const int wm  = w >> 1, wn = w & 1;
  const int x   = l & 15, h = l >> 4;

  int bx = blockIdx.x;
  int sw = ((bx & 7) << 7) | (bx >> 3);   // XCD swizzle (1024 % 8 == 0, bijective)
  const int g  = sw & 3;                  // M-tile (4 g's of one nt land on same XCD)
  const int nt = sw >> 2;                 // 0..255 : frames [nt*128, +128)

  // ---- stage audio segment once: evens/odds bf16 with position-based XOR swizzle ----
  {
    const long segbase = (long)(nt >> 3) * T_AUDIO;
    const int  f0 = (nt & 7) << 7;
    const int  sstart = f0 * 256 - PADL;
    const float* ap = audio + segbase;
    #pragma unroll
    for (int it = 0; it < 17; ++it){
      int p0 = (it * 256 + tid) * 8;
      if (p0 < SEGLEN){
        int sg = sstart + p0;
        float v[8];
        if (sg >= 0 && sg + 7 < T_AUDIO){
          f32x4 a0 = *(const f32x4*)(ap + sg);
          f32x4 a1 = *(const f32x4*)(ap + sg + 4);
          v[0]=a0[0]; v[1]=a0[1]; v[2]=a0[2]; v[3]=a0[3];
          v[4]=a1[0]; v[5]=a1[1]; v[6]=a1[2]; v[7]=a1[3];
        } else {
          #pragma unroll
          for (int e = 0; e < 8; ++e){
            int ss = sg + e;
            if (ss < 0) ss = -ss;
            if (ss >= T_AUDIO) ss = 2*(T_AUDIO-1) - ss;
            v[e] = ap[ss];
          }
        }
        unsigned long long pe = (unsigned long long)f2bf(v[0])
                              | ((unsigned long long)f2bf(v[2]) << 16)
                              | ((unsigned long long)f2bf(v[4]) << 32)
                              | ((unsigned long long)f2bf(v[6]) << 48);
        unsigned long long po = (unsigned long long)f2bf(v[1])
                              | ((unsigned long long)f2bf(v[3]) << 16)
                              | ((unsigned long long)f2bf(v[5]) << 32)
                              | ((unsigned long long)f2bf(v[7]) << 48);
        int ep = p0 >> 1;                       // even-array index (multiple of 4)
        int C  = ep >> 3;
        int ad = ((C ^ ((C >> 4) & 15)) << 4) + ((ep & 4) << 1);
        *(unsigned long long*)(LDS + ad)          = pe;
        *(unsigned long long*)(LDS + EBYTES + ad) = po;
      }
    }
  }
  __syncthreads();   // the ONLY barrier

  // ---- A frag-major bases (coalesced 1KB lines from L2) ----
  const char* AgE = (const char*)bi2f + (long)(g * 256 + wm * 4) * 1024 + l * 16;
  const char* AgO = AgE + 131072;

  // ---- B read chunk bases: C0[j] = t*16 + h, t = wn*64 + j*16 + x ----
  int C0[4];
  #pragma unroll
  for (int j = 0; j < 4; ++j) C0[j] = (wn * 64 + j * 16 + x) * 16 + h;

  f32x4 accE[4][4] = {}, accO[4][4] = {};
  bf16x8 aE[2][4], aO[2][4];
  #pragma unroll
  for (int i = 0; i < 4; ++i){
    aE[0][i] = *(const bf16x8*)(AgE + i * 1024);
    aO[0][i] = *(const bf16x8*)(AgO + i * 1024);
  }

  #pragma unroll
  for (int s = 0; s < 16; ++s){
    const int cur = s & 1, nxt = cur ^ 1;
    // prefetch next step's A frags (independent of this step's MFMAs)
    if (s < 15){
      #pragma unroll
      for (int i = 0; i < 4; ++i){
        aE[nxt][i] = *(const bf16x8*)(AgE + (s + 1) * 8192 + i * 1024);
        aO[nxt][i] = *(const bf16x8*)(AgO + (s + 1) * 8192 + i * 1024);
      }
    }
    // B frags from swizzled LDS (conflict-free)
    bf16x8 bqE[4], bqO[4];
    #pragma unroll
    for (int j = 0; j < 4; ++j){
      int C  = C0[j] + s * 4;
      int ad = (C ^ ((C >> 4) & 15)) << 4;
      bqE[j] = *(const bf16x8*)(LDS + ad);
      bqO[j] = *(const bf16x8*)(LDS + EBYTES + ad);
    }
    __builtin_amdgcn_s_setprio(1);
    #pragma unroll
    for (int i = 0; i < 4; ++i)
      #pragma unroll
      for (int j = 0; j < 4; ++j)
        accE[i][j] = __builtin_amdgcn_mfma_f32_16x16x32_bf16(aE[cur][i], bqE[j], accE[i][j], 0, 0, 0);
    #pragma unroll
    for (int i = 0; i < 4; ++i)
      #pragma unroll
      for (int j = 0; j < 4; ++j)
        accO[i][j] = __builtin_amdgcn_mfma_f32_16x16x32_bf16(aO[cur][i], bqO[j], accO[i][j], 0, 0, 0);
    __builtin_amdgcn_s_setprio(0);
  }

  // ---- epilogue: X[c]=E+O, X[512-c]=conj(E)-conj(O) -> |.| ----
  const long tbase = (long)(nt * 128 + wn * 64 + x);
  const int  q4 = h << 2;
  #pragma unroll
  for (int i = 0; i < 4; ++i){
    int mrow = wm * 64 + i * 16 + q4;       // multiple of 4
    int c0 = (g * 128 + mrow) >> 1;         // even, 0..254
    #pragma unroll
    for (int j = 0; j < 4; ++j){
      long t = tbase + j * 16;
      f32x4 E = accE[i][j], O = accO[i][j];
      float m1 = sqrtf((E[0]+O[0])*(E[0]+O[0]) + (E[1]+O[1])*(E[1]+O[1]));  // X[c0]
      float m2 = sqrtf((E[2]+O[2])*(E[2]+O[2]) + (E[3]+O[3])*(E[3]+O[3]));  // X[c0+1]
      float m3 = sqrtf((E[0]-O[0])*(E[0]-O[0]) + (E[1]-O[1])*(E[1]-O[1]));  // X[512-c0]
      float m4 = sqrtf((E[2]-O[2])*(E[2]-O[2]) + (E[3]-O[3])*(E[3]-O[3]));  // X[511-c0]
      unsigned pack = (unsigned)f2bf(m1) | ((unsigned)f2bf(m2) << 16);
      *(unsigned*)(magT + t * CPAD + c0) = pack;
      magT[t * CPAD + 512 - c0] = f2bf(m3);
      magT[t * CPAD + 511 - c0] = f2bf(m4);
    }
  }
}

// ---------- k_mel: [80][576] x [576][t] + log(clip) -> out [32][80][1024] f32 ----------
__launch_bounds__(256)
__global__ void k_mel(const unsigned short* __restrict__ wb,
                      const unsigned short* __restrict__ magT,
                      float* __restrict__ out){
  __shared__ unsigned short Ws[80 * 32];
  __shared__ unsigned short Ms[128 * 32];
  int tid  = threadIdx.x, lane = tid & 63, wid = tid >> 6;
  int bx   = blockIdx.x;
  int bt   = bx & 7, b = bx >> 3;
  int t0   = bt * 128;
  f32x4 acc[5][2] = {};
  const char* Mb = (const char*)(magT + ((long)b * 1024 + t0) * CPAD);
  const char* Wb = (const char*)wb;

  for (int kt = 0; kt < 18; ++kt){
    int k0b = kt * 64;
    {
      int o = tid * 16;
      gload_lds16(Wb + (o >> 6) * 1152 + k0b + (o & 63), (char*)Ws + wid * 1024);
      if (wid == 0){
        int o2 = 4096 + lane * 16;
        gload_lds16(Wb + (o2 >> 6) * 1152 + k0b + (o2 & 63), (char*)Ws + 4096);
      }
    }
    #pragma unroll
    for (int q = 0; q < 2; ++q){
      int o = (q * 256 + tid) * 16;
      gload_lds16(Mb + (long)(o >> 6) * 1152 + k0b + (o & 63), (char*)Ms + q * 4096 + wid * 1024);
    }
    __syncthreads();
    bf16x8 af[5], bfr[2];
    int kb = (lane >> 4) << 4;
    #pragma unroll
    for (int i = 0; i < 5; ++i)
      af[i] = *(const bf16x8*)((const char*)Ws + (i*16 + (lane & 15)) * 64 + kb);
    #pragma unroll
    for (int j = 0; j < 2; ++j)
      bfr[j] = *(const bf16x8*)((const char*)Ms + (wid*32 + j*16 + (lane & 15)) * 64 + kb);
    #pragma unroll
    for (int i = 0; i < 5; ++i)
      #pragma unroll
      for (int j = 0; j < 2; ++j)
        acc[i][j] = __builtin_amdgcn_mfma_f32_16x16x32_bf16(af[i], bfr[j], acc[i][j], 0, 0, 0);
    __syncthreads();
  }
  #pragma unroll
  for (int i = 0; i < 5; ++i)
    #pragma unroll
    for (int j = 0; j < 2; ++j){
      int m = i*16 + ((lane >> 4) << 2);
      int t = t0 + wid*32 + j*16 + (lane & 15);
      #pragma unroll
      for (int r = 0; r < 4; ++r){
        float v = acc[i][j][r];
        out[((long)b * NMELS + (m + r)) * 1024 + t] = logf(fmaxf(v, 1e-5f));
      }
    }
}

__global__ void k_sentinel(float* out, int n){
  int i = blockIdx.x * 256 + threadIdx.x;
  if (i < n) out[i] = 12345.0f;
}

extern "C" void kernel_launch(void* const* d_in, const int* in_sizes, int n_in,
                              void* d_out, int out_size, void* d_ws, size_t ws_size,
                              hipStream_t stream){
  const float* audio = (const float*)d_in[0];
  const float* basis = (const float*)d_in[1];
  const float* melw  = (const float*)d_in[2];
  float* out = (float*)d_out;

  size_t off_bi  = 0;                                            // bi2f: 1 MB
  size_t off_wb  = (size_t)2 * 1024 * 1024;
  size_t off_mag = off_wb + (size_t)NMELS * CPAD * 2;
  size_t total   = off_mag + (size_t)32 * 1024 * CPAD * 2;       // ~39.9 MB

  if (ws_size < total){
    k_sentinel<<<(out_size + 255) / 256, 256, 0, stream>>>(out, out_size);
    return;
  }
  char* ws = (char*)d_ws;
  unsigned short* bi2f = (unsigned short*)(ws + off_bi);
  unsigned short* wb   = (unsigned short*)(ws + off_wb);
  unsigned short* magT = (unsigned short*)(ws + off_mag);

  k_extra <<<16384, 256, 0, stream>>>(audio, basis, magT);
  k_basis4<<<  256, 256, 0, stream>>>(basis, bi2f);
  k_w     <<<  180, 256, 0, stream>>>(melw, wb);
  k_stft  <<< 1024, 256, 0, stream>>>(bi2f, audio, magT);
  k_mel   <<<  256, 256, 0, stream>>>(wb, magT, out);
}